// Round 3
// baseline (693.383 us; speedup 1.0000x reference)
//
#include <hip/hip_runtime.h>
#include <utility>
#include <cstddef>

// ---------------- compile-time Ivanic-Ruedenberg tables ----------------

struct Term { int o; int r; int a; float c; };
struct LTable { int n; Term t[1024]; };

constexpr double csqrt(double x) {
    if (x <= 0.0) return 0.0;
    double g = x < 1.0 ? 1.0 : x;
    for (int i = 0; i < 50; ++i) g = 0.5 * (g + x / g);
    return g;
}
constexpr int cabs_i(int x) { return x < 0 ? -x : x; }
constexpr int cmax_i(int a, int b) { return a > b ? a : b; }

constexpr void add_p(LTable& T, int o, double scale, int i, int a, int b, int l) {
    int lp = l - 1;
    int np = 2 * lp + 1;
    int row = i + 1;
    if (b == l) {
        T.t[T.n++] = Term{o, row * 3 + 2, (a + lp) * np + 2 * lp, (float)scale};
        T.t[T.n++] = Term{o, row * 3 + 0, (a + lp) * np + 0,      (float)(-scale)};
    } else if (b == -l) {
        T.t[T.n++] = Term{o, row * 3 + 2, (a + lp) * np + 0,      (float)scale};
        T.t[T.n++] = Term{o, row * 3 + 0, (a + lp) * np + 2 * lp, (float)scale};
    } else {
        T.t[T.n++] = Term{o, row * 3 + 1, (a + lp) * np + (b + lp), (float)scale};
    }
}

constexpr LTable ru_table(int l) {
    LTable T{};
    int n = 2 * l + 1;
    for (int m = -l; m <= l; ++m) {
        for (int mp = -l; mp <= l; ++mp) {
            double denom = (cabs_i(mp) == l) ? (double)((2 * l) * (2 * l - 1))
                                             : (double)((l + mp) * (l - mp));
            double d0 = (m == 0) ? 1.0 : 0.0;
            double u = csqrt((double)((l + m) * (l - m)) / denom);
            double v = 0.5 * csqrt((1.0 + d0) * (l + cabs_i(m) - 1) * (l + cabs_i(m)) / denom)
                       * (1.0 - 2.0 * d0);
            double w = -0.5 * csqrt((double)cmax_i(l - cabs_i(m) - 1, 0) * (l - cabs_i(m)) / denom)
                       * (1.0 - d0);
            int o = (m + l) * n + (mp + l);
            if (u != 0.0) add_p(T, o, u, 0, m, mp, l);
            if (v != 0.0) {
                if (m == 0) {
                    add_p(T, o, v, 1, 1, mp, l);
                    add_p(T, o, v, -1, -1, mp, l);
                } else if (m > 0) {
                    double s = (m == 1) ? csqrt(2.0) : 1.0;
                    add_p(T, o, v * s, 1, m - 1, mp, l);
                    if (m != 1) add_p(T, o, -v, -1, -m + 1, mp, l);
                } else {
                    if (m != -1) add_p(T, o, v, 1, m + 1, mp, l);
                    double s = (m == -1) ? csqrt(2.0) : 1.0;
                    add_p(T, o, v * s, -1, -m - 1, mp, l);
                }
            }
            if (w != 0.0) {
                if (m > 0) {
                    add_p(T, o, w, 1, m + 1, mp, l);
                    add_p(T, o, w, -1, -m - 1, mp, l);
                } else {
                    add_p(T, o, w, 1, m - 1, mp, l);
                    add_p(T, o, -w, -1, -m + 1, mp, l);
                }
            }
        }
    }
    return T;
}

inline constexpr LTable T2 = ru_table(2);
inline constexpr LTable T3 = ru_table(3);
inline constexpr LTable T4 = ru_table(4);

// terms for a given output entry are contiguous by construction (m-major, mp-minor)
template<const LTable& T>
constexpr int er_start(int e) {
    for (int i = 0; i < T.n; ++i) if (T.t[i].o == e) return i;
    return 0;
}
template<const LTable& T>
constexpr int er_cnt(int e) {
    int c = 0;
    for (int i = 0; i < T.n; ++i) if (T.t[i].o == e) ++c;
    return c;
}

// sum of terms, all operands in register arrays (compile-time indices only)
template<const LTable& T, int S, size_t... K>
__device__ __forceinline__ float sum_terms(const float* __restrict__ R1,
                                           const float* __restrict__ P,
                                           std::index_sequence<K...>) {
    float a = 0.0f;
    ((a = fmaf(T.t[S + (int)K].c, R1[T.t[S + (int)K].r] * P[T.t[S + (int)K].a], a)), ...);
    return a;
}

// build a whole level into a register array (no LDS involvement)
template<const LTable& T, size_t... E>
__device__ __forceinline__ void level_reg(const float* __restrict__ R1,
                                          const float* __restrict__ P,
                                          float* __restrict__ D,
                                          std::index_sequence<E...>) {
    ((D[(int)E] = sum_terms<T, er_start<T>((int)E)>(
          R1, P, std::make_index_sequence<er_cnt<T>((int)E)>{})), ...);
}

// ---------------- flat-entry evaluation ----------------

constexpr int lof(int R) { return R >= 16 ? 4 : R >= 9 ? 3 : R >= 4 ? 2 : R >= 1 ? 1 : 0; }

// value of flat entry f (f = 25*R + C) of one point's 25x25 D, from registers.
// l=0..3 come straight from register arrays; l=4 entries are computed on the
// fly from D3 via T4 (each l4 entry evaluated exactly once, except the 15
// entries in the overlap of the last two slices - idempotent rewrite).
template<int f>
__device__ __forceinline__ float entry_val(const float* __restrict__ R1,
                                           const float* __restrict__ D2,
                                           const float* __restrict__ D3) {
    constexpr int R = f / 25, C = f % 25;
    constexpr int lR = lof(R), lC = lof(C);
    if constexpr (lR != lC) {
        return 0.0f;
    } else if constexpr (lR == 0) {
        return 1.0f;
    } else if constexpr (lR == 1) {
        return R1[(R - 1) * 3 + (C - 1)];
    } else if constexpr (lR == 2) {
        return D2[(R - 4) * 5 + (C - 4)];
    } else if constexpr (lR == 3) {
        return D3[(R - 9) * 7 + (C - 9)];
    } else {
        constexpr int e = (R - 16) * 9 + (C - 16);
        constexpr int S4 = er_start<T4>(e);
        constexpr int C4 = er_cnt<T4>(e);
        return sum_terms<T4, S4>(R1, D3, std::make_index_sequence<C4>{});
    }
}

// native clang vector type: required by __builtin_nontemporal_store
typedef float v4f __attribute__((ext_vector_type(4)));

template<int S, int K>
__device__ __forceinline__ v4f make_chunk(const float* __restrict__ R1,
                                          const float* __restrict__ D2,
                                          const float* __restrict__ D3) {
    v4f v;
    v.x = entry_val<S + 4 * K + 0>(R1, D2, D3);
    v.y = entry_val<S + 4 * K + 1>(R1, D2, D3);
    v.z = entry_val<S + 4 * K + 2>(R1, D2, D3);
    v.w = entry_val<S + 4 * K + 3>(R1, D2, D3);
    return v;
}

// lane writes its own 64-value slice row: 16 x ds_write_b128.
// strip row stride = 68 floats (272 B, 16B-aligned). Bank math for a b128
// wave-inst at fixed K: bank-quad = (17*lane + K) % 8 -> 8 lanes per quad,
// distinct addresses: exactly the 1KB/128B-per-cyc BW floor (no extra cost).
template<int S, size_t... K>
__device__ __forceinline__ void write_slice(v4f* __restrict__ vrow,
                                            const float* __restrict__ R1,
                                            const float* __restrict__ D2,
                                            const float* __restrict__ D3,
                                            std::index_sequence<K...>) {
    ((vrow[(int)K] = make_chunk<S, (int)K>(R1, D2, D3)), ...);
}

// one 64-column slice: lane-major write -> fence -> transposed read + NT store.
// Read: strip[68*j + lane] -> bank (4j+lane)%32: lane and lane+32 share a bank
// = free 2-way. Store: 64 lanes x 4B = 256 B contiguous per inst, 4B-aligned
// everywhere (no v4f global stores: point rows are 2500 B = not 16B-aligned).
// 'full' is wave-uniform: fast path has zero branches in the store loop.
template<int S>
__device__ __forceinline__ void emit_slice(v4f* __restrict__ vrow,
                                           const float* __restrict__ strip,
                                           float* __restrict__ obase,
                                           long long wbase, int lane, int Ntot,
                                           bool full,
                                           const float* __restrict__ R1,
                                           const float* __restrict__ D2,
                                           const float* __restrict__ D3) {
    write_slice<S>(vrow, R1, D2, D3, std::make_index_sequence<16>{});
    // all 16 ds_writes retired before any lane reads transposed data
    asm volatile("s_waitcnt lgkmcnt(0)" ::: "memory");
    if (full) {
#pragma unroll
        for (int j = 0; j < 64; ++j) {
            __builtin_nontemporal_store(strip[68 * j + lane], obase + S + 625 * j);
        }
    } else {
#pragma unroll 1
        for (int j = 0; j < 64; ++j) {
            if (wbase + j < Ntot) {
                __builtin_nontemporal_store(strip[68 * j + lane], obase + S + 625 * j);
            }
        }
    }
    // keep next slice's ds_writes from being hoisted above these ds_reads
    asm volatile("" ::: "memory");
}

// ---------------- fused kernel ----------------
// BARRIER-FREE wave-private pipelines (vs rounds 0/1, whose block-wide
// scatter->sync->copy->sync convoy let HBM writes flow only ~40% of the
// time). Each wave owns 64 points (one per lane) and a private LDS strip of
// 64x68 floats (17,408 B; 4 waves -> 69,632 B -> 2 blocks/CU).
// Per lane: compute R1, D2, D3 fully in registers (83 live floats, fits the
// 128-VGPR cap as proven by the round-0 kernel), then emit the 625-column
// output row as ten 64-column slices through the strip:
//   write own row slice (16 ds_write_b128) -> s_waitcnt lgkmcnt(0) ->
//   transposed read (64 ds_read_b32) + coalesced nontemporal stores.
// No __syncthreads anywhere: within a wave, cross-lane LDS RAW is ordered by
// the lgkmcnt fence; WAR (next slice's writes vs this slice's reads) is safe
// because a wave's DS ops execute in issue order and the NT stores consume
// the read data before the next slice's writes issue. 8 independent wave
// pipelines per CU keep the HBM write pipe continuously busy.
// 625 = 9*64 + 49: the last slice starts at column 561 and rewrites columns
// 561..575 with identical values (idempotent, also for the global stores).

__global__ __launch_bounds__(256, 2)
void wigner_fused_kernel(const float* __restrict__ xyz, float* __restrict__ out, int Ntot) {
    __shared__ __align__(16) float lds[4 * 64 * 68];

    const int t = threadIdx.x;
    const int w = t >> 6;
    const int lane = t & 63;
    float* __restrict__ strip = lds + w * (64 * 68);

    const long long wbase = (long long)blockIdx.x * 256 + (long long)w * 64;
    if (wbase >= Ntot) return;  // wave-uniform; no barriers in this kernel
    const long long pt = wbase + lane;
    const bool full = (wbase + 64 <= (long long)Ntot);  // wave-uniform

    float x = 0.0f, y = 0.0f, z = 1.0f;
    if (pt < Ntot) {
        x = xyz[3 * pt + 0];
        y = xyz[3 * pt + 1];
        z = xyz[3 * pt + 2];
    }

    // trig without trig: ct = vz (clipped), st = sqrt(1-ct^2), cp/sp from x,y
    const float r2 = x * x + y * y + z * z;
    const float rinv = rsqrtf(fmaxf(r2, 1e-24f));
    const float ct = fminf(fmaxf(z * rinv, -1.0f), 1.0f);
    const float st = sqrtf(fmaxf(1.0f - ct * ct, 0.0f));
    const float rxy2 = x * x + y * y;
    float cp = 1.0f, sp = 0.0f;
    if (rxy2 > 0.0f) {
        const float ri = rsqrtf(rxy2);
        cp = x * ri;
        sp = y * ri;
    }

    // R1 in real-SH l=1 basis order (y,z,x), row-major 3x3
    const float R1[9] = {cp,      0.0f, -sp,
                         st * sp, ct,   st * cp,
                         ct * sp, -st,  ct * cp};

    float D2[25];
    level_reg<T2>(R1, R1, D2, std::make_index_sequence<25>{});
    float D3[49];
    level_reg<T3>(R1, D2, D3, std::make_index_sequence<49>{});

    v4f* __restrict__ vrow = (v4f*)(strip + 68 * lane);
    float* __restrict__ obase = out + wbase * 625 + lane;

    emit_slice<0  >(vrow, strip, obase, wbase, lane, Ntot, full, R1, D2, D3);
    emit_slice<64 >(vrow, strip, obase, wbase, lane, Ntot, full, R1, D2, D3);
    emit_slice<128>(vrow, strip, obase, wbase, lane, Ntot, full, R1, D2, D3);
    emit_slice<192>(vrow, strip, obase, wbase, lane, Ntot, full, R1, D2, D3);
    emit_slice<256>(vrow, strip, obase, wbase, lane, Ntot, full, R1, D2, D3);
    emit_slice<320>(vrow, strip, obase, wbase, lane, Ntot, full, R1, D2, D3);
    emit_slice<384>(vrow, strip, obase, wbase, lane, Ntot, full, R1, D2, D3);
    emit_slice<448>(vrow, strip, obase, wbase, lane, Ntot, full, R1, D2, D3);
    emit_slice<512>(vrow, strip, obase, wbase, lane, Ntot, full, R1, D2, D3);
    emit_slice<561>(vrow, strip, obase, wbase, lane, Ntot, full, R1, D2, D3);
}

extern "C" void kernel_launch(void* const* d_in, const int* in_sizes, int n_in,
                              void* d_out, int out_size, void* d_ws, size_t ws_size,
                              hipStream_t stream) {
    const float* xyz = (const float*)d_in[0];
    float* out = (float*)d_out;
    const int N = in_sizes[0] / 3;
    const int blocks = (N + 255) / 256;
    hipLaunchKernelGGL(wigner_fused_kernel, dim3(blocks), dim3(256), 0, stream,
                       xyz, out, N);
}

// Round 4
// 538.579 us; speedup vs baseline: 1.2874x; 1.2874x over previous
//
#include <hip/hip_runtime.h>
#include <utility>
#include <cstddef>

// ---------------- compile-time Ivanic-Ruedenberg tables ----------------

struct Term { int o; int r; int a; float c; };
struct LTable { int n; Term t[1024]; };

constexpr double csqrt(double x) {
    if (x <= 0.0) return 0.0;
    double g = x < 1.0 ? 1.0 : x;
    for (int i = 0; i < 50; ++i) g = 0.5 * (g + x / g);
    return g;
}
constexpr int cabs_i(int x) { return x < 0 ? -x : x; }
constexpr int cmax_i(int a, int b) { return a > b ? a : b; }

constexpr void add_p(LTable& T, int o, double scale, int i, int a, int b, int l) {
    int lp = l - 1;
    int np = 2 * lp + 1;
    int row = i + 1;
    if (b == l) {
        T.t[T.n++] = Term{o, row * 3 + 2, (a + lp) * np + 2 * lp, (float)scale};
        T.t[T.n++] = Term{o, row * 3 + 0, (a + lp) * np + 0,      (float)(-scale)};
    } else if (b == -l) {
        T.t[T.n++] = Term{o, row * 3 + 2, (a + lp) * np + 0,      (float)scale};
        T.t[T.n++] = Term{o, row * 3 + 0, (a + lp) * np + 2 * lp, (float)scale};
    } else {
        T.t[T.n++] = Term{o, row * 3 + 1, (a + lp) * np + (b + lp), (float)scale};
    }
}

constexpr LTable ru_table(int l) {
    LTable T{};
    int n = 2 * l + 1;
    for (int m = -l; m <= l; ++m) {
        for (int mp = -l; mp <= l; ++mp) {
            double denom = (cabs_i(mp) == l) ? (double)((2 * l) * (2 * l - 1))
                                             : (double)((l + mp) * (l - mp));
            double d0 = (m == 0) ? 1.0 : 0.0;
            double u = csqrt((double)((l + m) * (l - m)) / denom);
            double v = 0.5 * csqrt((1.0 + d0) * (l + cabs_i(m) - 1) * (l + cabs_i(m)) / denom)
                       * (1.0 - 2.0 * d0);
            double w = -0.5 * csqrt((double)cmax_i(l - cabs_i(m) - 1, 0) * (l - cabs_i(m)) / denom)
                       * (1.0 - d0);
            int o = (m + l) * n + (mp + l);
            if (u != 0.0) add_p(T, o, u, 0, m, mp, l);
            if (v != 0.0) {
                if (m == 0) {
                    add_p(T, o, v, 1, 1, mp, l);
                    add_p(T, o, v, -1, -1, mp, l);
                } else if (m > 0) {
                    double s = (m == 1) ? csqrt(2.0) : 1.0;
                    add_p(T, o, v * s, 1, m - 1, mp, l);
                    if (m != 1) add_p(T, o, -v, -1, -m + 1, mp, l);
                } else {
                    if (m != -1) add_p(T, o, v, 1, m + 1, mp, l);
                    double s = (m == -1) ? csqrt(2.0) : 1.0;
                    add_p(T, o, v * s, -1, -m - 1, mp, l);
                }
            }
            if (w != 0.0) {
                if (m > 0) {
                    add_p(T, o, w, 1, m + 1, mp, l);
                    add_p(T, o, w, -1, -m - 1, mp, l);
                } else {
                    add_p(T, o, w, 1, m - 1, mp, l);
                    add_p(T, o, -w, -1, -m + 1, mp, l);
                }
            }
        }
    }
    return T;
}

inline constexpr LTable T2 = ru_table(2);
inline constexpr LTable T3 = ru_table(3);
inline constexpr LTable T4 = ru_table(4);

// terms for a given output entry are contiguous by construction (m-major, mp-minor)
template<const LTable& T>
constexpr int er_start(int e) {
    for (int i = 0; i < T.n; ++i) if (T.t[i].o == e) return i;
    return 0;
}
template<const LTable& T>
constexpr int er_cnt(int e) {
    int c = 0;
    for (int i = 0; i < T.n; ++i) if (T.t[i].o == e) ++c;
    return c;
}

template<const LTable& T, int S, size_t... K>
__device__ __forceinline__ float sum_terms(const float* __restrict__ R1,
                                           const float* __restrict__ P,
                                           std::index_sequence<K...>) {
    float a = 0.0f;
    ((a = fmaf(T.t[S + (int)K].c, R1[T.t[S + (int)K].r] * P[T.t[S + (int)K].a], a)), ...);
    return a;
}

// compute one entry of block l, optionally keep in array, stream ds_write to row
template<const LTable& T, int l, bool KEEP, int e>
__device__ __forceinline__ void level_one(const float* __restrict__ R1,
                                          const float* __restrict__ P,
                                          float* __restrict__ keep,
                                          float* __restrict__ row) {
    constexpr int S = er_start<T>(e);
    constexpr int C = er_cnt<T>(e);
    float v = sum_terms<T, S>(R1, P, std::make_index_sequence<C>{});
    if constexpr (KEEP) keep[e] = v;
    constexpr int d = 2 * l + 1;
    constexpr int r = e / d, c = e % d;
    constexpr int E625 = (l * l + r) * 25 + (l * l + c);  // ds_write imm offset
    row[E625] = v;
}

template<const LTable& T, int l, bool KEEP, size_t... E>
__device__ __forceinline__ void level(const float* __restrict__ R1,
                                      const float* __restrict__ P,
                                      float* __restrict__ keep,
                                      float* __restrict__ row,
                                      std::index_sequence<E...>) {
    (level_one<T, l, KEEP, (int)E>(R1, P, keep, row), ...);
}

template<size_t... E>
__device__ __forceinline__ void write_l1(const float* __restrict__ D1,
                                         float* __restrict__ row,
                                         std::index_sequence<E...>) {
    ((row[(1 + (int)E / 3) * 25 + (1 + (int)E % 3)] = D1[E]), ...);
}

// native clang vector type: required by __builtin_nontemporal_store
typedef float v4f __attribute__((ext_vector_type(4)));

// ---------------- light barrier ----------------
// __syncthreads() compiles to s_waitcnt vmcnt(0) lgkmcnt(0) + s_barrier: it
// drains ALL in-flight nontemporal HBM stores at every chunk boundary (the
// round-0/1 structural tax; counters showed both pipes idle). The only
// ordering the image actually needs at these barriers is LDS: scatter
// ds_writes visible before copy ds_reads, and copy ds_reads retired before
// the next scatter overwrites. NT stores read their VGPRs at issue and never
// need a barrier-side drain (end-of-kernel waits them). So: lgkm-only drain
// + raw s_barrier, memory-clobber fenced so the compiler can't move LDS ops
// across (guide rule #18 / HipKittens pattern).
__device__ __forceinline__ void bar_lgkm() {
    asm volatile("s_waitcnt lgkmcnt(0)" ::: "memory");
    __builtin_amdgcn_s_barrier();
    asm volatile("" ::: "memory");
}

// ---------------- fused kernel ----------------
// Block: 256 threads = 256 points, 8 chunks of 32 points.
// LDS image 32x625 floats (80,000 B) -> 2 blocks/CU.
// Per chunk: the 32 owning threads RECOMPUTE their D from 4 live trig regs,
// streaming each entry into the image via compile-time-immediate ds_writes
// (one base register; bank = (17*p0+E)%32, permutation in p0 -> conflict-free).
// D4 is never materialized as an array: peak live floats = D1+D2+D3 = 83.
// Structural zeros written once at block start; l=0's 1.0 written per scatter.
// Copy phase: contiguous 16B-aligned nontemporal v4f stream (1 KB/wave-inst).
// vs round 0: the ONLY change is bar_lgkm() replacing __syncthreads(), so
// HBM stores from chunk c stay in flight under chunk c+1's scatter/copy.

__global__ __launch_bounds__(256, 2)
void wigner_fused_kernel(const float* __restrict__ xyz, float* __restrict__ out, int Ntot) {
    __shared__ float img[32 * 625];

    const int t = threadIdx.x;
    const int gp = blockIdx.x * 256 + t;

    float x = 0.0f, y = 0.0f, z = 1.0f;
    if (gp < Ntot) {
        x = xyz[3 * gp + 0];
        y = xyz[3 * gp + 1];
        z = xyz[3 * gp + 2];
    }

    // trig without trig: ct = vz (clipped), st = sqrt(1-ct^2), cp/sp from x,y
    const float r2 = x * x + y * y + z * z;
    const float rinv = rsqrtf(fmaxf(r2, 1e-24f));
    const float ct = fminf(fmaxf(z * rinv, -1.0f), 1.0f);
    const float st = sqrtf(fmaxf(1.0f - ct * ct, 0.0f));
    const float rxy2 = x * x + y * y;
    float cp = 1.0f, sp = 0.0f;
    if (rxy2 > 0.0f) {
        const float ri = rsqrtf(rxy2);
        cp = x * ri;
        sp = y * ri;
    }
    // only ct, st, cp, sp stay live across the chunk loop (4 VGPRs)

    // zero whole image once (zero-structure slots never rewritten)
    v4f* b4 = (v4f*)img;
    const v4f z4 = {0.0f, 0.0f, 0.0f, 0.0f};
#pragma unroll 4
    for (int k = t; k < 5000; k += 256) b4[k] = z4;
    bar_lgkm();

    const int p0 = t & 31;
    const long long blk_f = (long long)blockIdx.x * 256 * 625;

    for (int c = 0; c < 8; ++c) {
        const int base_pt = blockIdx.x * 256 + c * 32;
        if (base_pt >= Ntot) break;  // uniform across block
        const int vp = min(32, Ntot - base_pt);

        // scatter: owning 32 threads recompute D and stream into the image
        if ((t >> 5) == c && gp < Ntot) {
            float* __restrict__ row = img + p0 * 625;
            row[0] = 1.0f;  // l=0 block

            // R1 in real-SH l=1 basis order (y,z,x), row-major 3x3
            float D1[9] = {cp,      0.0f, -sp,
                           st * sp, ct,   st * cp,
                           ct * sp, -st,  ct * cp};
            write_l1(D1, row, std::make_index_sequence<9>{});

            float D2[25];
            level<T2, 2, true>(D1, D1, D2, row, std::make_index_sequence<25>{});
            float D3[49];
            level<T3, 3, true>(D1, D2, D3, row, std::make_index_sequence<49>{});
            level<T4, 4, false>(D1, D3, nullptr, row, std::make_index_sequence<81>{});
        }
        bar_lgkm();  // scatter ds_writes visible to all waves; stores NOT drained

        const long long out_f = blk_f + (long long)c * 32 * 625;
        if (vp == 32) {
            const v4f* src = (const v4f*)img;
            v4f* dst = (v4f*)(out + out_f);
#pragma unroll 4
            for (int k = t; k < 5000; k += 256) {
                __builtin_nontemporal_store(src[k], dst + k);
            }
        } else {
            const int vf = vp * 625;
            for (int k = t; k < vf; k += 256) {
                out[out_f + k] = img[k];
            }
        }
        bar_lgkm();  // copy ds_reads retired; next scatter may overwrite image
    }
}

extern "C" void kernel_launch(void* const* d_in, const int* in_sizes, int n_in,
                              void* d_out, int out_size, void* d_ws, size_t ws_size,
                              hipStream_t stream) {
    const float* xyz = (const float*)d_in[0];
    float* out = (float*)d_out;
    const int N = in_sizes[0] / 3;
    const int blocks = (N + 255) / 256;
    hipLaunchKernelGGL(wigner_fused_kernel, dim3(blocks), dim3(256), 0, stream,
                       xyz, out, N);
}

// Round 5
// 535.236 us; speedup vs baseline: 1.2955x; 1.0062x over previous
//
#include <hip/hip_runtime.h>
#include <utility>
#include <cstddef>

// ---------------- compile-time Ivanic-Ruedenberg tables ----------------

struct Term { int o; int r; int a; float c; };
struct LTable { int n; Term t[1024]; };

constexpr double csqrt(double x) {
    if (x <= 0.0) return 0.0;
    double g = x < 1.0 ? 1.0 : x;
    for (int i = 0; i < 50; ++i) g = 0.5 * (g + x / g);
    return g;
}
constexpr int cabs_i(int x) { return x < 0 ? -x : x; }
constexpr int cmax_i(int a, int b) { return a > b ? a : b; }

constexpr void add_p(LTable& T, int o, double scale, int i, int a, int b, int l) {
    int lp = l - 1;
    int np = 2 * lp + 1;
    int row = i + 1;
    if (b == l) {
        T.t[T.n++] = Term{o, row * 3 + 2, (a + lp) * np + 2 * lp, (float)scale};
        T.t[T.n++] = Term{o, row * 3 + 0, (a + lp) * np + 0,      (float)(-scale)};
    } else if (b == -l) {
        T.t[T.n++] = Term{o, row * 3 + 2, (a + lp) * np + 0,      (float)scale};
        T.t[T.n++] = Term{o, row * 3 + 0, (a + lp) * np + 2 * lp, (float)scale};
    } else {
        T.t[T.n++] = Term{o, row * 3 + 1, (a + lp) * np + (b + lp), (float)scale};
    }
}

constexpr LTable ru_table(int l) {
    LTable T{};
    int n = 2 * l + 1;
    for (int m = -l; m <= l; ++m) {
        for (int mp = -l; mp <= l; ++mp) {
            double denom = (cabs_i(mp) == l) ? (double)((2 * l) * (2 * l - 1))
                                             : (double)((l + mp) * (l - mp));
            double d0 = (m == 0) ? 1.0 : 0.0;
            double u = csqrt((double)((l + m) * (l - m)) / denom);
            double v = 0.5 * csqrt((1.0 + d0) * (l + cabs_i(m) - 1) * (l + cabs_i(m)) / denom)
                       * (1.0 - 2.0 * d0);
            double w = -0.5 * csqrt((double)cmax_i(l - cabs_i(m) - 1, 0) * (l - cabs_i(m)) / denom)
                       * (1.0 - d0);
            int o = (m + l) * n + (mp + l);
            if (u != 0.0) add_p(T, o, u, 0, m, mp, l);
            if (v != 0.0) {
                if (m == 0) {
                    add_p(T, o, v, 1, 1, mp, l);
                    add_p(T, o, v, -1, -1, mp, l);
                } else if (m > 0) {
                    double s = (m == 1) ? csqrt(2.0) : 1.0;
                    add_p(T, o, v * s, 1, m - 1, mp, l);
                    if (m != 1) add_p(T, o, -v, -1, -m + 1, mp, l);
                } else {
                    if (m != -1) add_p(T, o, v, 1, m + 1, mp, l);
                    double s = (m == -1) ? csqrt(2.0) : 1.0;
                    add_p(T, o, v * s, -1, -m - 1, mp, l);
                }
            }
            if (w != 0.0) {
                if (m > 0) {
                    add_p(T, o, w, 1, m + 1, mp, l);
                    add_p(T, o, w, -1, -m - 1, mp, l);
                } else {
                    add_p(T, o, w, 1, m - 1, mp, l);
                    add_p(T, o, -w, -1, -m + 1, mp, l);
                }
            }
        }
    }
    return T;
}

inline constexpr LTable T2 = ru_table(2);
inline constexpr LTable T3 = ru_table(3);
inline constexpr LTable T4 = ru_table(4);

// terms for a given output entry are contiguous by construction (m-major, mp-minor)
template<const LTable& T>
constexpr int er_start(int e) {
    for (int i = 0; i < T.n; ++i) if (T.t[i].o == e) return i;
    return 0;
}
template<const LTable& T>
constexpr int er_cnt(int e) {
    int c = 0;
    for (int i = 0; i < T.n; ++i) if (T.t[i].o == e) ++c;
    return c;
}

template<const LTable& T, int S, size_t... K>
__device__ __forceinline__ float sum_terms(const float* __restrict__ R1,
                                           const float* __restrict__ P,
                                           std::index_sequence<K...>) {
    float a = 0.0f;
    ((a = fmaf(T.t[S + (int)K].c, R1[T.t[S + (int)K].r] * P[T.t[S + (int)K].a], a)), ...);
    return a;
}

// compute one entry of block l, optionally keep in array, stream ds_write to row
template<const LTable& T, int l, bool KEEP, int e>
__device__ __forceinline__ void level_one(const float* __restrict__ R1,
                                          const float* __restrict__ P,
                                          float* __restrict__ keep,
                                          float* __restrict__ row) {
    constexpr int S = er_start<T>(e);
    constexpr int C = er_cnt<T>(e);
    float v = sum_terms<T, S>(R1, P, std::make_index_sequence<C>{});
    if constexpr (KEEP) keep[e] = v;
    constexpr int d = 2 * l + 1;
    constexpr int r = e / d, c = e % d;
    constexpr int E625 = (l * l + r) * 25 + (l * l + c);  // ds_write imm offset
    row[E625] = v;
}

template<const LTable& T, int l, bool KEEP, size_t... E>
__device__ __forceinline__ void level(const float* __restrict__ R1,
                                      const float* __restrict__ P,
                                      float* __restrict__ keep,
                                      float* __restrict__ row,
                                      std::index_sequence<E...>) {
    (level_one<T, l, KEEP, (int)E>(R1, P, keep, row), ...);
}

template<size_t... E>
__device__ __forceinline__ void write_l1(const float* __restrict__ D1,
                                         float* __restrict__ row,
                                         std::index_sequence<E...>) {
    ((row[(1 + (int)E / 3) * 25 + (1 + (int)E % 3)] = D1[E]), ...);
}

typedef float v4f __attribute__((ext_vector_type(4)));

// ---------------- light barrier ----------------
// lgkm-only drain + raw s_barrier (round-4 A/B showed this is neutral vs
// __syncthreads, so it's kept: strictly never worse, and it guarantees HBM
// stores are not drained at chunk boundaries).
__device__ __forceinline__ void bar_lgkm() {
    asm volatile("s_waitcnt lgkmcnt(0)" ::: "memory");
    __builtin_amdgcn_s_barrier();
    asm volatile("" ::: "memory");
}

// ---------------- fused kernel ----------------
// Block: 256 threads = 256 points, 8 chunks of 32 points.
// LDS image 32x625 floats (80,000 B) -> 2 blocks/CU.
// Per chunk: the 32 owning threads RECOMPUTE their D from 4 live trig regs,
// streaming each entry into the image via compile-time-immediate ds_writes
// (one base register; bank = (17*p0+E)%32, permutation in p0 -> conflict-free).
// D4 is never materialized as an array: peak live floats = D1+D2+D3 = 83.
// Structural zeros written once at block start; l=0's 1.0 written per scatter.
// Copy phase: contiguous 16B-aligned v4f stream (1 KB/wave-inst).
//
// vs round 4, the ONLY change: plain (L2-routed) stores instead of
// __builtin_nontemporal_store. Evidence for the swap: (a) round-3's
// barrier-free NT streamer plateaued at 1.84 TB/s with all pipes idle --
// store-path ceiling signature; (b) the harness fill kernel proves plain
// stores reach 6.2 TB/s at 10% occupancy; (c) NT bypasses L2, losing write
// combining/buffering. Output is write-once so L2 eviction is harmless.

__global__ __launch_bounds__(256, 2)
void wigner_fused_kernel(const float* __restrict__ xyz, float* __restrict__ out, int Ntot) {
    __shared__ float img[32 * 625];

    const int t = threadIdx.x;
    const int gp = blockIdx.x * 256 + t;

    float x = 0.0f, y = 0.0f, z = 1.0f;
    if (gp < Ntot) {
        x = xyz[3 * gp + 0];
        y = xyz[3 * gp + 1];
        z = xyz[3 * gp + 2];
    }

    // trig without trig: ct = vz (clipped), st = sqrt(1-ct^2), cp/sp from x,y
    const float r2 = x * x + y * y + z * z;
    const float rinv = rsqrtf(fmaxf(r2, 1e-24f));
    const float ct = fminf(fmaxf(z * rinv, -1.0f), 1.0f);
    const float st = sqrtf(fmaxf(1.0f - ct * ct, 0.0f));
    const float rxy2 = x * x + y * y;
    float cp = 1.0f, sp = 0.0f;
    if (rxy2 > 0.0f) {
        const float ri = rsqrtf(rxy2);
        cp = x * ri;
        sp = y * ri;
    }
    // only ct, st, cp, sp stay live across the chunk loop (4 VGPRs)

    // zero whole image once (zero-structure slots never rewritten)
    v4f* b4 = (v4f*)img;
    const v4f z4 = {0.0f, 0.0f, 0.0f, 0.0f};
#pragma unroll 4
    for (int k = t; k < 5000; k += 256) b4[k] = z4;
    bar_lgkm();

    const int p0 = t & 31;
    const long long blk_f = (long long)blockIdx.x * 256 * 625;

    for (int c = 0; c < 8; ++c) {
        const int base_pt = blockIdx.x * 256 + c * 32;
        if (base_pt >= Ntot) break;  // uniform across block
        const int vp = min(32, Ntot - base_pt);

        // scatter: owning 32 threads recompute D and stream into the image
        if ((t >> 5) == c && gp < Ntot) {
            float* __restrict__ row = img + p0 * 625;
            row[0] = 1.0f;  // l=0 block

            // R1 in real-SH l=1 basis order (y,z,x), row-major 3x3
            float D1[9] = {cp,      0.0f, -sp,
                           st * sp, ct,   st * cp,
                           ct * sp, -st,  ct * cp};
            write_l1(D1, row, std::make_index_sequence<9>{});

            float D2[25];
            level<T2, 2, true>(D1, D1, D2, row, std::make_index_sequence<25>{});
            float D3[49];
            level<T3, 3, true>(D1, D2, D3, row, std::make_index_sequence<49>{});
            level<T4, 4, false>(D1, D3, nullptr, row, std::make_index_sequence<81>{});
        }
        bar_lgkm();  // scatter ds_writes visible to all waves

        const long long out_f = blk_f + (long long)c * 32 * 625;
        if (vp == 32) {
            const v4f* src = (const v4f*)img;
            v4f* dst = (v4f*)(out + out_f);
#pragma unroll 4
            for (int k = t; k < 5000; k += 256) {
                dst[k] = src[k];  // plain L2-routed store (NOT nontemporal)
            }
        } else {
            const int vf = vp * 625;
            for (int k = t; k < vf; k += 256) {
                out[out_f + k] = img[k];
            }
        }
        bar_lgkm();  // copy ds_reads retired; next scatter may overwrite image
    }
}

extern "C" void kernel_launch(void* const* d_in, const int* in_sizes, int n_in,
                              void* d_out, int out_size, void* d_ws, size_t ws_size,
                              hipStream_t stream) {
    const float* xyz = (const float*)d_in[0];
    float* out = (float*)d_out;
    const int N = in_sizes[0] / 3;
    const int blocks = (N + 255) / 256;
    hipLaunchKernelGGL(wigner_fused_kernel, dim3(blocks), dim3(256), 0, stream,
                       xyz, out, N);
}